// Round 1
// baseline (143.060 us; speedup 1.0000x reference)
//
#include <hip/hip_runtime.h>

// Problem constants (from reference setup_inputs)
#define BATCH 256
#define SEQ   2048
#define VOCAB 128000
#define HASH  4096   // 2x SEQ -> load factor 0.5 for linear probing

// One block per batch row, 256 threads, each thread owns 8 elements:
//   i = 4*t + k        (k=0..3)   first half  via float4/int4 at offset t
//   i = 1024 + 4*t + k (k=0..3)   second half via float4/int4 at offset 256+t
__global__ __launch_bounds__(256)
void softmax_scatter_kernel(const float* __restrict__ w_es,
                            const int*   __restrict__ x,
                            float* __restrict__ w_a,     // [BATCH, VOCAB], pre-zeroed
                            float* __restrict__ w_out)   // [BATCH, SEQ]
{
    __shared__ int   key [HASH];   // token id or -1
    __shared__ int   maxi[HASH];   // max position index seen for this token
    __shared__ float red[8];       // [0..3] max partials, [4..7] sum partials

    const int r = blockIdx.x;
    const int t = threadIdx.x;
    const int lane = t & 63;
    const int wid  = t >> 6;       // 4 waves of 64

    // ---- init hash table (barrier before use is covered by reduction syncs) ----
    for (int j = t; j < HASH; j += 256) { key[j] = -1; maxi[j] = -1; }

    // ---- load scores, vectorized ----
    const float* rowp = w_es + (size_t)r * SEQ;
    const float4 a0 = ((const float4*)rowp)[t];
    const float4 a1 = ((const float4*)rowp)[256 + t];

    // ---- block max ----
    float m = fmaxf(fmaxf(fmaxf(a0.x, a0.y), fmaxf(a0.z, a0.w)),
                    fmaxf(fmaxf(a1.x, a1.y), fmaxf(a1.z, a1.w)));
    #pragma unroll
    for (int off = 32; off > 0; off >>= 1)
        m = fmaxf(m, __shfl_down(m, off, 64));
    if (lane == 0) red[wid] = m;
    __syncthreads();
    m = fmaxf(fmaxf(red[0], red[1]), fmaxf(red[2], red[3]));

    // ---- exp + block sum ----
    float e[8];
    e[0] = __expf(a0.x - m); e[1] = __expf(a0.y - m);
    e[2] = __expf(a0.z - m); e[3] = __expf(a0.w - m);
    e[4] = __expf(a1.x - m); e[5] = __expf(a1.y - m);
    e[6] = __expf(a1.z - m); e[7] = __expf(a1.w - m);
    float s = e[0] + e[1] + e[2] + e[3] + e[4] + e[5] + e[6] + e[7];
    #pragma unroll
    for (int off = 32; off > 0; off >>= 1)
        s += __shfl_down(s, off, 64);
    if (lane == 0) red[4 + wid] = s;
    __syncthreads();
    s = red[4] + red[5] + red[6] + red[7];

    const float inv = 1.0f / s;
    float w[8];
    #pragma unroll
    for (int k = 0; k < 8; ++k) w[k] = e[k] * inv;

    // ---- write weights output (coalesced float4) ----
    float* wrow = w_out + (size_t)r * SEQ;
    ((float4*)wrow)[t]       = make_float4(w[0], w[1], w[2], w[3]);
    ((float4*)wrow)[256 + t] = make_float4(w[4], w[5], w[6], w[7]);

    // ---- load token ids ----
    const int* xrow = x + (size_t)r * SEQ;
    const int4 x0 = ((const int4*)xrow)[t];
    const int4 x1 = ((const int4*)xrow)[256 + t];
    int tok[8] = { x0.x, x0.y, x0.z, x0.w, x1.x, x1.y, x1.z, x1.w };
    int idx[8];
    #pragma unroll
    for (int k = 0; k < 4; ++k) { idx[k] = 4 * t + k; idx[4 + k] = 1024 + 4 * t + k; }

    // ---- insert into LDS hash: claim slot with CAS, track max position ----
    // Slots are write-once, so every holder of token T converges to the same
    // slot (first slot in T's deterministic probe sequence that contains T).
    int slot[8];
    #pragma unroll
    for (int k = 0; k < 8; ++k) {
        unsigned h = (((unsigned)tok[k] * 2654435761u) >> 16) & (HASH - 1);
        int sl = (int)h;
        while (true) {
            int prev = atomicCAS(&key[sl], -1, tok[k]);
            if (prev == -1 || prev == tok[k]) break;
            sl = (sl + 1) & (HASH - 1);
        }
        slot[k] = sl;
        atomicMax(&maxi[sl], idx[k]);
    }
    __syncthreads();

    // ---- exactly one winner per distinct token: the max-i holder (numpy
    //      last-write-wins semantics) stores its weight ----
    float* warow = w_a + (size_t)r * VOCAB;
    #pragma unroll
    for (int k = 0; k < 8; ++k) {
        if (maxi[slot[k]] == idx[k])
            warow[tok[k]] = w[k];
    }
}

extern "C" void kernel_launch(void* const* d_in, const int* in_sizes, int n_in,
                              void* d_out, int out_size, void* d_ws, size_t ws_size,
                              hipStream_t stream) {
    const float* w_es = (const float*)d_in[0];
    const int*   x    = (const int*)d_in[1];

    float* out  = (float*)d_out;
    float* w_a  = out;                          // [256, 128000]
    float* w    = out + (size_t)BATCH * VOCAB;  // [256, 2048]

    // Zero the scatter target (d_out is poisoned 0xAA before every launch).
    hipMemsetAsync(w_a, 0, (size_t)BATCH * VOCAB * sizeof(float), stream);

    softmax_scatter_kernel<<<BATCH, 256, 0, stream>>>(w_es, x, w_a, w);
}